// Round 1
// baseline (1455.990 us; speedup 1.0000x reference)
//
#include <hip/hip_runtime.h>
#include <hip/hip_bf16.h>
#include <math.h>

#define SLEN 2048
#define DIM 256
#define NB 4
#define NKF 24
#define NH 1024
#define NROW (NB*SLEN)          // 8192
#define NTOT (NB*SLEN*DIM)      // 2097152

#define BM 128
#define BN 256
#define BKK 32
#define PADK 40                 // padded LDS row stride (bf16 elems)

typedef __attribute__((ext_vector_type(8))) short bf16x8;
typedef __attribute__((ext_vector_type(4))) float f32x4;

struct __align__(16) U4 { unsigned int a, b, c, d; };
struct __align__(8)  S4 { unsigned short x, y, z, w; };

__device__ __forceinline__ unsigned short f2b(float v){
    union { __hip_bfloat16 h; unsigned short u; } cv;
    cv.h = __float2bfloat16(v);
    return cv.u;
}
__device__ __forceinline__ float b2f(unsigned short s){
    union { __hip_bfloat16 h; unsigned short u; } cv;
    cv.u = s;
    return __bfloat162float(cv.h);
}

// ---------------- small elementwise kernels ----------------

__global__ void k_cast(const float* __restrict__ src, unsigned short* __restrict__ dst, int n){
    int i = blockIdx.x*256 + threadIdx.x;
    if (i < n) dst[i] = f2b(src[i]);
}

__global__ void k_transpose(const float* __restrict__ src, unsigned short* __restrict__ dst, int R, int C){
    int i = blockIdx.x*256 + threadIdx.x;
    if (i < R*C){ int r = i / C, c = i - r*C; dst[(size_t)c*R + r] = f2b(src[i]); }
}

// build M = [[A1, A2],[I, 0]] into pow[1] (row-major) and powT[1] (transposed)
__global__ void k_buildM(const float* __restrict__ my, unsigned short* __restrict__ pw, unsigned short* __restrict__ pwT){
    int i = blockIdx.x*256 + threadIdx.x;
    if (i >= 512*512) return;
    int r = i >> 9, c = i & 511;
    float v;
    if (r < 256) v = (c < 256) ? my[r*256 + c] : my[256*256 + r*256 + (c - 256)];
    else         v = (c == r - 256) ? 1.0f : 0.0f;
    unsigned short bb = f2b(v);
    pw [262144 + (size_t)r*512 + c] = bb;
    pwT[262144 + (size_t)c*512 + r] = bb;
}

__global__ void k_rmsnorm(const float* __restrict__ x, const float* __restrict__ w, unsigned short* __restrict__ u){
    int row = blockIdx.x;          // 8192
    int t = threadIdx.x;           // 256
    float v = x[(size_t)row*DIM + t];
    float ss = v*v;
    #pragma unroll
    for (int o = 32; o > 0; o >>= 1) ss += __shfl_down(ss, o, 64);
    __shared__ float red[4];
    if ((t & 63) == 0) red[t >> 6] = ss;
    __syncthreads();
    float tot = red[0]+red[1]+red[2]+red[3];
    float sc = rsqrtf(tot * (1.0f/256.0f) + 1e-6f);
    u[(size_t)row*DIM + t] = f2b(v * sc * w[t]);
}

__global__ void k_yinit(const float* __restrict__ y, float* __restrict__ yh, unsigned short* __restrict__ yb){
    int i = blockIdx.x*256 + threadIdx.x;
    if (i < NTOT){ float v = y[i]; yh[i] = v; yb[i] = f2b(v); }
}

__global__ void k_act(const unsigned short* __restrict__ h1T, const unsigned short* __restrict__ gT,
                      unsigned short* __restrict__ actT){
    int i = blockIdx.x*256 + threadIdx.x;
    if (i < NH*NROW){
        float a = b2f(h1T[i]);
        float g = b2f(gT[i]);
        float s = a / (1.0f + expf(-a));
        actT[i] = f2b(s * g);
    }
}

__global__ void k_outinit(const float* __restrict__ x, const float* __restrict__ yh, float* __restrict__ out){
    int i = blockIdx.x*256 + threadIdx.x;
    if (i < NTOT) out[i] = x[i] + yh[i];
}

// ---------------- shared MFMA tile core ----------------
// 128x256 tile, 8 waves (2x4), each wave 64x64 = 4x4 frags of 16x16, K-step 32.

__device__ __forceinline__ void mfma_tile(const unsigned short* Al, const unsigned short* Bl,
                                          f32x4 acc[4][4], int lane, int wr, int wc){
    int cl = lane & 15;
    int kb = (lane >> 4) * 8;
    bf16x8 a[4], b[4];
    #pragma unroll
    for (int mi = 0; mi < 4; ++mi)
        a[mi] = *(const bf16x8*)&Al[(wr*64 + mi*16 + cl)*PADK + kb];
    #pragma unroll
    for (int ni = 0; ni < 4; ++ni)
        b[ni] = *(const bf16x8*)&Bl[(wc*64 + ni*16 + cl)*PADK + kb];
    #pragma unroll
    for (int mi = 0; mi < 4; ++mi)
        #pragma unroll
        for (int ni = 0; ni < 4; ++ni)
            acc[mi][ni] = __builtin_amdgcn_mfma_f32_16x16x32_bf16(a[mi], b[ni], acc[mi][ni], 0, 0, 0);
}

#define GEMM_PROLOG \
    __shared__ unsigned short Al[BM*PADK]; \
    __shared__ unsigned short Bl[BN*PADK]; \
    int tid = threadIdx.x, lane = tid & 63, wv = tid >> 6, wr = wv >> 2, wc = wv & 3; \
    f32x4 acc[4][4]; \
    { f32x4 z = {0.f,0.f,0.f,0.f}; \
      for (int mi=0;mi<4;++mi) for (int ni=0;ni<4;++ni) acc[mi][ni] = z; }

// ---------------- batched power doubling: pow[n+j] = pow[n] * pow[j] ----------------
__global__ __launch_bounds__(512) void k_pow(unsigned short* __restrict__ pw, unsigned short* __restrict__ pwT,
                                             int n, int jbase){
    GEMM_PROLOG
    int mt = blockIdx.x, nt = blockIdx.y;
    int j = jbase + blockIdx.z;
    int p = n + j;
    const unsigned short* A = pw  + (size_t)n * 262144;
    const unsigned short* B = pwT + (size_t)j * 262144;
    int m0 = mt * BM, n0 = nt * BN;
    for (int k0 = 0; k0 < 512; k0 += BKK){
        __syncthreads();
        { int row = tid >> 2, sg = tid & 3;
          *(U4*)&Al[row*PADK + sg*8] = *(const U4*)&A[(size_t)(m0+row)*512 + k0 + sg*8]; }
        #pragma unroll
        for (int s = 0; s < 2; ++s){ int q = tid + s*512; int row = q >> 2, sg = q & 3;
          *(U4*)&Bl[row*PADK + sg*8] = *(const U4*)&B[(size_t)(n0+row)*512 + k0 + sg*8]; }
        __syncthreads();
        mfma_tile(Al, Bl, acc, lane, wr, wc);
    }
    int cl = lane & 15, rg = (lane >> 4) * 4;
    #pragma unroll
    for (int mi=0; mi<4; ++mi){
        int rb = m0 + wr*64 + mi*16 + rg;
        #pragma unroll
        for (int ni=0; ni<4; ++ni){
            int col = n0 + wc*64 + ni*16 + cl;
            #pragma unroll
            for (int r=0;r<4;++r) pw[(size_t)p*262144 + (size_t)(rb+r)*512 + col] = f2b(acc[mi][ni][r]);
            if (p < 32){
                S4 pk; pk.x=f2b(acc[mi][ni][0]); pk.y=f2b(acc[mi][ni][1]); pk.z=f2b(acc[mi][ni][2]); pk.w=f2b(acc[mi][ni][3]);
                *(S4*)&pwT[(size_t)p*262144 + (size_t)col*512 + rb] = pk;
            }
        }
    }
}

// ---------------- ar_u: y = sum_i shift(u,i) @ M_u[i]^T ----------------
__global__ __launch_bounds__(512) void k_aru(const unsigned short* __restrict__ u,
                                             const unsigned short* __restrict__ Mu, float* __restrict__ y){
    GEMM_PROLOG
    int tt = blockIdx.x, b = blockIdx.y;
    int t0 = tt * BM;
    const unsigned short* Ab = u + (size_t)b*SLEN*DIM;
    for (int i = 0; i < 3; ++i){
        const unsigned short* Bsrc = Mu + (size_t)i*65536;
        for (int k0 = 0; k0 < 256; k0 += BKK){
            __syncthreads();
            { int row = tid >> 2, sg = tid & 3; int t = t0 + row - i;
              U4 val; val.a=val.b=val.c=val.d=0u;
              if (t >= 0) val = *(const U4*)&Ab[(size_t)t*DIM + k0 + sg*8];
              *(U4*)&Al[row*PADK + sg*8] = val; }
            #pragma unroll
            for (int s = 0; s < 2; ++s){ int q = tid + s*512; int row = q >> 2, sg = q & 3;
              *(U4*)&Bl[row*PADK + sg*8] = *(const U4*)&Bsrc[(size_t)row*DIM + k0 + sg*8]; }
            __syncthreads();
            mfma_tile(Al, Bl, acc, lane, wr, wc);
        }
    }
    int cl = lane & 15, rg = (lane >> 4) * 4;
    #pragma unroll
    for (int mi=0; mi<4; ++mi){
        int tb = t0 + wr*64 + mi*16 + rg;
        #pragma unroll
        for (int ni=0; ni<4; ++ni){
            int o = wc*64 + ni*16 + cl;
            #pragma unroll
            for (int r=0;r<4;++r) y[((size_t)b*SLEN + tb + r)*DIM + o] = acc[mi][ni][r];
        }
    }
}

// ---------------- projection: V[k][b][o][t] = sr_k * (alt_t) * (u @ Mk^T) ----------------
__global__ __launch_bounds__(512) void k_proj(const unsigned short* __restrict__ u,
                                              const unsigned short* __restrict__ Mb,
                                              const float* __restrict__ sigma,
                                              unsigned short* __restrict__ V, int minus){
    GEMM_PROLOG
    int tt = blockIdx.x, b = blockIdx.y, k = blockIdx.z;
    int t0 = tt * BM;
    float sr = powf(sigma[k], 0.25f);
    const unsigned short* Asrc = u + ((size_t)b*SLEN + t0)*DIM;
    const unsigned short* Bsrc = Mb + (size_t)k*65536;
    for (int k0 = 0; k0 < 256; k0 += BKK){
        __syncthreads();
        { int row = tid >> 2, sg = tid & 3;
          *(U4*)&Al[row*PADK + sg*8] = *(const U4*)&Asrc[(size_t)row*DIM + k0 + sg*8]; }
        #pragma unroll
        for (int s = 0; s < 2; ++s){ int q = tid + s*512; int row = q >> 2, sg = q & 3;
          *(U4*)&Bl[row*PADK + sg*8] = *(const U4*)&Bsrc[(size_t)row*DIM + k0 + sg*8]; }
        __syncthreads();
        mfma_tile(Al, Bl, acc, lane, wr, wc);
    }
    int cl = lane & 15, rg = (lane >> 4) * 4;
    #pragma unroll
    for (int mi=0; mi<4; ++mi){
        int tb = t0 + wr*64 + mi*16 + rg;
        #pragma unroll
        for (int ni=0; ni<4; ++ni){
            int o = wc*64 + ni*16 + cl;
            S4 pk;
            float s0 = (minus && ((tb+0)&1)) ? -sr : sr;
            float s1 = (minus && ((tb+1)&1)) ? -sr : sr;
            float s2 = (minus && ((tb+2)&1)) ? -sr : sr;
            float s3 = (minus && ((tb+3)&1)) ? -sr : sr;
            pk.x = f2b(acc[mi][ni][0]*s0); pk.y = f2b(acc[mi][ni][1]*s1);
            pk.z = f2b(acc[mi][ni][2]*s2); pk.w = f2b(acc[mi][ni][3]*s3);
            *(S4*)&V[(((size_t)k*NB + b)*DIM + o)*SLEN + tb] = pk;
        }
    }
}

// ---------------- causal Toeplitz conv: y += sum_k T_k @ V[k]  ----------------
__global__ __launch_bounds__(512) void k_conv(const unsigned short* __restrict__ V,
                                              const unsigned short* __restrict__ phiT,
                                              float* __restrict__ y){
    GEMM_PROLOG
    int jx = blockIdx.x, b = blockIdx.y;
    int tt, cnt = 0;
    for (tt = 0; tt < 16; ++tt){ cnt = (tt + 2) >> 1; if (jx < cnt) break; jx -= cnt; }
    int t0 = tt * BM, tau0 = jx * 256;
    for (int k = 0; k < NKF; ++k){
        const unsigned short* phik = phiT + (size_t)k*SLEN;
        const unsigned short* Vkb  = V + (((size_t)k*NB + b)*DIM)*SLEN;
        for (int ssb = 0; ssb < 8; ++ssb){
            int ts = tau0 + ssb*BKK;
            __syncthreads();
            { int row = tid >> 2, sg = tid & 3;
              int t = t0 + row;
              union { U4 v; unsigned short s[8]; } pk;
              #pragma unroll
              for (int e = 0; e < 8; ++e){
                  int dl = t - (ts + sg*8 + e);
                  pk.s[e] = (dl >= 0) ? phik[dl] : (unsigned short)0;
              }
              *(U4*)&Al[row*PADK + sg*8] = pk.v; }
            #pragma unroll
            for (int s = 0; s < 2; ++s){ int q = tid + s*512; int row = q >> 2, sg = q & 3;
              *(U4*)&Bl[row*PADK + sg*8] = *(const U4*)&Vkb[(size_t)row*SLEN + ts + sg*8]; }
            __syncthreads();
            mfma_tile(Al, Bl, acc, lane, wr, wc);
        }
    }
    int cl = lane & 15, rg = (lane >> 4) * 4;
    #pragma unroll
    for (int mi=0; mi<4; ++mi){
        int tb = t0 + wr*64 + mi*16 + rg;
        #pragma unroll
        for (int ni=0; ni<4; ++ni){
            int o = wc*64 + ni*16 + cl;
            #pragma unroll
            for (int r=0;r<4;++r) atomicAdd(&y[((size_t)b*SLEN + tb + r)*DIM + o], acc[mi][ni][r]);
        }
    }
}

// ---------------- output AR via truncated Q-filter: yhat += sum_{p>=1} Q_p y_{t-p} ----------------
__global__ __launch_bounds__(512) void k_qconv(const unsigned short* __restrict__ yb,
                                               const unsigned short* __restrict__ pw,
                                               float* __restrict__ yh){
    GEMM_PROLOG
    int tt = blockIdx.x, b = blockIdx.y, g = blockIdx.z;
    int t0 = tt * BM;
    const unsigned short* ysrc = yb + (size_t)b*SLEN*DIM;
    for (int pi = 0; pi < 8; ++pi){
        int p = g*8 + pi;
        if (p == 0) continue;
        const unsigned short* Q = pw + (size_t)p*262144;   // Q_p[o][d] = pow[p][o*512+d]
        for (int k0 = 0; k0 < 256; k0 += BKK){
            __syncthreads();
            { int row = tid >> 2, sg = tid & 3; int t = t0 + row - p;
              U4 val; val.a=val.b=val.c=val.d=0u;
              if (t >= 0) val = *(const U4*)&ysrc[(size_t)t*DIM + k0 + sg*8];
              *(U4*)&Al[row*PADK + sg*8] = val; }
            #pragma unroll
            for (int s = 0; s < 2; ++s){ int q = tid + s*512; int row = q >> 2, sg = q & 3;
              *(U4*)&Bl[row*PADK + sg*8] = *(const U4*)&Q[(size_t)row*512 + k0 + sg*8]; }
            __syncthreads();
            mfma_tile(Al, Bl, acc, lane, wr, wc);
        }
    }
    int cl = lane & 15, rg = (lane >> 4) * 4;
    #pragma unroll
    for (int mi=0; mi<4; ++mi){
        int tb = t0 + wr*64 + mi*16 + rg;
        #pragma unroll
        for (int ni=0; ni<4; ++ni){
            int o = wc*64 + ni*16 + cl;
            #pragma unroll
            for (int r=0;r<4;++r) atomicAdd(&yh[((size_t)b*SLEN + tb + r)*DIM + o], acc[mi][ni][r]);
        }
    }
}

// ---------------- MLP GEMM1 (w1 and v fused over n-tiles), outputs transposed [h][bt] ----------------
__global__ __launch_bounds__(512) void k_mlp1(const unsigned short* __restrict__ hb,
                                              const unsigned short* __restrict__ w1T,
                                              const unsigned short* __restrict__ vT,
                                              unsigned short* __restrict__ h1T,
                                              unsigned short* __restrict__ gT){
    GEMM_PROLOG
    int tt = blockIdx.x, b = blockIdx.y, nt = blockIdx.z;
    int t0 = tt * BM;
    const unsigned short* Bsrc = (nt < 4) ? (w1T + (size_t)nt*256*256) : (vT + (size_t)(nt-4)*256*256);
    unsigned short* dst = (nt < 4) ? h1T : gT;
    int h0 = (nt & 3) * 256;
    const unsigned short* Asrc = hb + ((size_t)b*SLEN + t0)*DIM;
    for (int k0 = 0; k0 < 256; k0 += BKK){
        __syncthreads();
        { int row = tid >> 2, sg = tid & 3;
          *(U4*)&Al[row*PADK + sg*8] = *(const U4*)&Asrc[(size_t)row*DIM + k0 + sg*8]; }
        #pragma unroll
        for (int s = 0; s < 2; ++s){ int q = tid + s*512; int row = q >> 2, sg = q & 3;
          *(U4*)&Bl[row*PADK + sg*8] = *(const U4*)&Bsrc[(size_t)row*DIM + k0 + sg*8]; }
        __syncthreads();
        mfma_tile(Al, Bl, acc, lane, wr, wc);
    }
    int cl = lane & 15, rg = (lane >> 4) * 4;
    #pragma unroll
    for (int mi=0; mi<4; ++mi){
        int btb = b*SLEN + t0 + wr*64 + mi*16 + rg;
        #pragma unroll
        for (int ni=0; ni<4; ++ni){
            int hcol = h0 + wc*64 + ni*16 + cl;
            S4 pk;
            pk.x = f2b(acc[mi][ni][0]); pk.y = f2b(acc[mi][ni][1]);
            pk.z = f2b(acc[mi][ni][2]); pk.w = f2b(acc[mi][ni][3]);
            *(S4*)&dst[(size_t)hcol*NROW + btb] = pk;
        }
    }
}

// ---------------- MLP GEMM2: out += act @ w2 (K split, A transpose-staged from actT) ----------------
__global__ __launch_bounds__(512) void k_mlp2(const unsigned short* __restrict__ actT,
                                              const unsigned short* __restrict__ w2T,
                                              float* __restrict__ out){
    GEMM_PROLOG
    int tt = blockIdx.x, b = blockIdx.y, ks = blockIdx.z;
    int t0 = tt * BM;
    int bt0 = b*SLEN + t0;
    for (int k0 = ks*256; k0 < ks*256 + 256; k0 += BKK){
        __syncthreads();
        { int hj = tid & 31, tsg = tid >> 5;   // hj: K-col 0..31, tsg: 0..15
          const unsigned short* src = &actT[(size_t)(k0 + hj)*NROW + bt0 + tsg*8];
          union { U4 v; unsigned short s[8]; } pk;
          pk.v = *(const U4*)src;
          #pragma unroll
          for (int e = 0; e < 8; ++e) Al[(tsg*8 + e)*PADK + hj] = pk.s[e];
        }
        #pragma unroll
        for (int s = 0; s < 2; ++s){ int q = tid + s*512; int row = q >> 2, sg = q & 3;
          *(U4*)&Bl[row*PADK + sg*8] = *(const U4*)&w2T[(size_t)row*NH + k0 + sg*8]; }
        __syncthreads();
        mfma_tile(Al, Bl, acc, lane, wr, wc);
    }
    int cl = lane & 15, rg = (lane >> 4) * 4;
    #pragma unroll
    for (int mi=0; mi<4; ++mi){
        int tb = t0 + wr*64 + mi*16 + rg;
        #pragma unroll
        for (int ni=0; ni<4; ++ni){
            int o = wc*64 + ni*16 + cl;
            #pragma unroll
            for (int r=0;r<4;++r) atomicAdd(&out[((size_t)b*SLEN + tb + r)*DIM + o], acc[mi][ni][r]);
        }
    }
}

// ---------------- host ----------------

extern "C" void kernel_launch(void* const* d_in, const int* in_sizes, int n_in,
                              void* d_out, int out_size, void* d_ws, size_t ws_size,
                              hipStream_t stream) {
    (void)in_sizes; (void)n_in; (void)out_size;
    const float* x     = (const float*)d_in[0];
    const float* sigma = (const float*)d_in[1];
    const float* phi   = (const float*)d_in[2];
    const float* rmsw  = (const float*)d_in[3];
    const float* Mu    = (const float*)d_in[4];
    const float* Mp    = (const float*)d_in[5];
    const float* Mm    = (const float*)d_in[6];
    const float* my    = (const float*)d_in[7];
    const float* w1    = (const float*)d_in[8];
    const float* vv    = (const float*)d_in[9];
    const float* w2    = (const float*)d_in[10];
    float* out = (float*)d_out;

    char* ws = (char*)d_ws;
    size_t off = 0;
    auto alloc = [&](size_t bytes){ size_t o = off; off += (bytes + 255) & ~(size_t)255; return o; };

    size_t o_u    = alloc((size_t)NROW*DIM*2);
    size_t o_phiT = alloc((size_t)NKF*SLEN*2);
    size_t o_MuB  = alloc((size_t)3*65536*2);
    size_t o_MpB  = alloc((size_t)NKF*65536*2);
    size_t o_MmB  = alloc((size_t)NKF*65536*2);
    size_t o_w1T  = alloc((size_t)NH*DIM*2);
    size_t o_vT   = alloc((size_t)NH*DIM*2);
    size_t o_w2T  = alloc((size_t)DIM*NH*2);
    size_t o_pow  = alloc((size_t)64*512*512*2);
    size_t o_powT = alloc((size_t)32*512*512*2);
    size_t o_V    = alloc((size_t)NKF*NB*DIM*SLEN*2);
    size_t o_y    = alloc((size_t)NTOT*4);
    size_t o_yhat = alloc((size_t)NTOT*4);
    size_t o_ybf  = alloc((size_t)NTOT*2);
    size_t o_yhbf = alloc((size_t)NTOT*2);
    size_t o_h1T  = alloc((size_t)NH*NROW*2);
    size_t o_gT   = alloc((size_t)NH*NROW*2);
    size_t o_actT = alloc((size_t)NH*NROW*2);
    if (off > ws_size) return;   // insufficient workspace — fail visibly

    unsigned short* u_b  = (unsigned short*)(ws + o_u);
    unsigned short* phiT = (unsigned short*)(ws + o_phiT);
    unsigned short* MuB  = (unsigned short*)(ws + o_MuB);
    unsigned short* MpB  = (unsigned short*)(ws + o_MpB);
    unsigned short* MmB  = (unsigned short*)(ws + o_MmB);
    unsigned short* w1T  = (unsigned short*)(ws + o_w1T);
    unsigned short* vT   = (unsigned short*)(ws + o_vT);
    unsigned short* w2T  = (unsigned short*)(ws + o_w2T);
    unsigned short* pw   = (unsigned short*)(ws + o_pow);
    unsigned short* pwT  = (unsigned short*)(ws + o_powT);
    unsigned short* V    = (unsigned short*)(ws + o_V);
    float* y     = (float*)(ws + o_y);
    float* yhat  = (float*)(ws + o_yhat);
    unsigned short* ybf  = (unsigned short*)(ws + o_ybf);
    unsigned short* yhbf = (unsigned short*)(ws + o_yhbf);
    unsigned short* h1T  = (unsigned short*)(ws + o_h1T);
    unsigned short* gT   = (unsigned short*)(ws + o_gT);
    unsigned short* actT = (unsigned short*)(ws + o_actT);

    // weight conversions
    k_cast<<<dim3((3*65536+255)/256), 256, 0, stream>>>(Mu, MuB, 3*65536);
    k_cast<<<dim3((NKF*65536+255)/256), 256, 0, stream>>>(Mp, MpB, NKF*65536);
    k_cast<<<dim3((NKF*65536+255)/256), 256, 0, stream>>>(Mm, MmB, NKF*65536);
    k_transpose<<<dim3((SLEN*NKF+255)/256), 256, 0, stream>>>(phi, phiT, SLEN, NKF);
    k_transpose<<<dim3((DIM*NH+255)/256), 256, 0, stream>>>(w1, w1T, DIM, NH);
    k_transpose<<<dim3((DIM*NH+255)/256), 256, 0, stream>>>(vv, vT, DIM, NH);
    k_transpose<<<dim3((NH*DIM+255)/256), 256, 0, stream>>>(w2, w2T, NH, DIM);
    k_buildM<<<dim3(1024), 256, 0, stream>>>(my, pw, pwT);

    // rmsnorm
    k_rmsnorm<<<dim3(NROW), 256, 0, stream>>>(x, rmsw, u_b);

    // companion-matrix powers via doubling (bf16, f32 accumulate)
    const int ns[6]   = {1, 2, 4, 8, 16, 32};
    const int cnts[6] = {1, 2, 4, 8, 16, 31};
    for (int s = 0; s < 6; ++s)
        k_pow<<<dim3(4, 2, cnts[s]), 512, 0, stream>>>(pw, pwT, ns[s], 1);

    // y = ar_u
    k_aru<<<dim3(16, NB), 512, 0, stream>>>(u_b, MuB, y);

    // spectral: two passes (plus, minus) reusing V
    for (int pm = 0; pm < 2; ++pm){
        k_proj<<<dim3(16, NB, NKF), 512, 0, stream>>>(u_b, pm ? MmB : MpB, sigma, V, pm);
        k_conv<<<dim3(72, NB), 512, 0, stream>>>(V, phiT, y);
    }

    // output AR recurrence via truncated Q-filter (P=64)
    k_yinit<<<dim3((NTOT+255)/256), 256, 0, stream>>>(y, yhat, ybf);
    k_qconv<<<dim3(16, NB, 8), 512, 0, stream>>>(ybf, pw, yhat);
    k_cast<<<dim3((NTOT+255)/256), 256, 0, stream>>>(yhat, yhbf, NTOT);

    // MLP + residuals
    k_mlp1<<<dim3(16, NB, 8), 512, 0, stream>>>(yhbf, w1T, vT, h1T, gT);
    k_act<<<dim3((NH*NROW+255)/256), 256, 0, stream>>>(h1T, gT, actT);
    k_outinit<<<dim3((NTOT+255)/256), 256, 0, stream>>>(x, yhat, out);
    k_mlp2<<<dim3(16, NB, 4), 512, 0, stream>>>(actT, w2T, out);
}

// Round 2
// 1056.128 us; speedup vs baseline: 1.3786x; 1.3786x over previous
//
#include <hip/hip_runtime.h>
#include <hip/hip_bf16.h>
#include <math.h>

#define SLEN 2048
#define DIM 256
#define NB 4
#define NKF 24
#define NH 1024
#define NROW (NB*SLEN)          // 8192
#define NTOT (NB*SLEN*DIM)      // 2097152

#define BM 128
#define BN 256
#define BKK 32
#define PADK 40                 // padded LDS row stride (bf16 elems) for generic GEMMs

// conv-specific
#define KG 3                    // k-group blocks
#define KPB 8                   // filters per block
#define PCOPY 4                 // shifted copies of reversed phi window
#define PHIW 392                // padded copy length (384 used + pad, 196 words: bank-offset 4/copy)

typedef __attribute__((ext_vector_type(8))) short bf16x8;
typedef __attribute__((ext_vector_type(4))) short bf16x4;
typedef __attribute__((ext_vector_type(4))) float f32x4;

struct __align__(16) U4 { unsigned int a, b, c, d; };
struct __align__(8)  S4 { unsigned short x, y, z, w; };

__device__ __forceinline__ unsigned short f2b(float v){
    union { __hip_bfloat16 h; unsigned short u; } cv;
    cv.h = __float2bfloat16(v);
    return cv.u;
}
__device__ __forceinline__ float b2f(unsigned short s){
    union { __hip_bfloat16 h; unsigned short u; } cv;
    cv.u = s;
    return __bfloat162float(cv.h);
}

// ---------------- small elementwise kernels ----------------

__global__ void k_cast4(const float4* __restrict__ src, S4* __restrict__ dst, int n4){
    int i = blockIdx.x*256 + threadIdx.x;
    if (i < n4){
        float4 v = src[i];
        S4 p; p.x = f2b(v.x); p.y = f2b(v.y); p.z = f2b(v.z); p.w = f2b(v.w);
        dst[i] = p;
    }
}

__global__ void k_transpose(const float* __restrict__ src, unsigned short* __restrict__ dst, int R, int C){
    int i = blockIdx.x*256 + threadIdx.x;
    if (i < R*C){ int r = i / C, c = i - r*C; dst[(size_t)c*R + r] = f2b(src[i]); }
}

// build M = [[A1, A2],[I, 0]] into pow[1] (row-major) and powT[1] (transposed)
__global__ void k_buildM(const float* __restrict__ my, unsigned short* __restrict__ pw, unsigned short* __restrict__ pwT){
    int i = blockIdx.x*256 + threadIdx.x;
    if (i >= 512*512) return;
    int r = i >> 9, c = i & 511;
    float v;
    if (r < 256) v = (c < 256) ? my[r*256 + c] : my[256*256 + r*256 + (c - 256)];
    else         v = (c == r - 256) ? 1.0f : 0.0f;
    unsigned short bb = f2b(v);
    pw [262144 + (size_t)r*512 + c] = bb;
    pwT[262144 + (size_t)c*512 + r] = bb;
}

__global__ void k_rmsnorm(const float* __restrict__ x, const float* __restrict__ w, unsigned short* __restrict__ u){
    int row = blockIdx.x;          // 8192
    int t = threadIdx.x;           // 256
    float v = x[(size_t)row*DIM + t];
    float ss = v*v;
    #pragma unroll
    for (int o = 32; o > 0; o >>= 1) ss += __shfl_down(ss, o, 64);
    __shared__ float red[4];
    if ((t & 63) == 0) red[t >> 6] = ss;
    __syncthreads();
    float tot = red[0]+red[1]+red[2]+red[3];
    float sc = rsqrtf(tot * (1.0f/256.0f) + 1e-6f);
    u[(size_t)row*DIM + t] = f2b(v * sc * w[t]);
}

__global__ void k_yinit(const float4* __restrict__ y, float4* __restrict__ yh, S4* __restrict__ yb){
    int i = blockIdx.x*256 + threadIdx.x;
    if (i < NTOT/4){
        float4 v = y[i];
        yh[i] = v;
        S4 p; p.x = f2b(v.x); p.y = f2b(v.y); p.z = f2b(v.z); p.w = f2b(v.w);
        yb[i] = p;
    }
}

__global__ void k_act(const U4* __restrict__ h1T, const U4* __restrict__ gT, U4* __restrict__ actT){
    int i = blockIdx.x*256 + threadIdx.x;
    if (i < NH*NROW/8){
        union { U4 v; unsigned short s[8]; } a, g, r;
        a.v = h1T[i]; g.v = gT[i];
        #pragma unroll
        for (int e = 0; e < 8; ++e){
            float av = b2f(a.s[e]);
            float gv = b2f(g.s[e]);
            float sv = av / (1.0f + expf(-av));
            r.s[e] = f2b(sv * gv);
        }
        actT[i] = r.v;
    }
}

__global__ void k_outinit(const float4* __restrict__ x, const float4* __restrict__ yh, float4* __restrict__ out){
    int i = blockIdx.x*256 + threadIdx.x;
    if (i < NTOT/4){
        float4 a = x[i], b = yh[i];
        float4 r; r.x = a.x+b.x; r.y = a.y+b.y; r.z = a.z+b.z; r.w = a.w+b.w;
        out[i] = r;
    }
}

// ---------------- shared MFMA tile core (generic GEMMs) ----------------
// 128x256 tile, 8 waves (2x4), each wave 64x64 = 4x4 frags of 16x16, K-step 32.

__device__ __forceinline__ void mfma_tile(const unsigned short* Al, const unsigned short* Bl,
                                          f32x4 acc[4][4], int lane, int wr, int wc){
    int cl = lane & 15;
    int kb = (lane >> 4) * 8;
    bf16x8 a[4], b[4];
    #pragma unroll
    for (int mi = 0; mi < 4; ++mi)
        a[mi] = *(const bf16x8*)&Al[(wr*64 + mi*16 + cl)*PADK + kb];
    #pragma unroll
    for (int ni = 0; ni < 4; ++ni)
        b[ni] = *(const bf16x8*)&Bl[(wc*64 + ni*16 + cl)*PADK + kb];
    #pragma unroll
    for (int mi = 0; mi < 4; ++mi)
        #pragma unroll
        for (int ni = 0; ni < 4; ++ni)
            acc[mi][ni] = __builtin_amdgcn_mfma_f32_16x16x32_bf16(a[mi], b[ni], acc[mi][ni], 0, 0, 0);
}

#define GEMM_PROLOG \
    __shared__ unsigned short Al[BM*PADK]; \
    __shared__ unsigned short Bl[BN*PADK]; \
    int tid = threadIdx.x, lane = tid & 63, wv = tid >> 6, wr = wv >> 2, wc = wv & 3; \
    f32x4 acc[4][4]; \
    { f32x4 z = {0.f,0.f,0.f,0.f}; \
      for (int mi=0;mi<4;++mi) for (int ni=0;ni<4;++ni) acc[mi][ni] = z; }

// ---------------- batched power doubling: pow[n+j] = pow[n] * pow[j] ----------------
__global__ __launch_bounds__(512) void k_pow(unsigned short* __restrict__ pw, unsigned short* __restrict__ pwT,
                                             int n, int jbase){
    GEMM_PROLOG
    int mt = blockIdx.x, nt = blockIdx.y;
    int j = jbase + blockIdx.z;
    int p = n + j;
    const unsigned short* A = pw  + (size_t)n * 262144;
    const unsigned short* B = pwT + (size_t)j * 262144;
    int m0 = mt * BM, n0 = nt * BN;
    for (int k0 = 0; k0 < 512; k0 += BKK){
        __syncthreads();
        { int row = tid >> 2, sg = tid & 3;
          *(U4*)&Al[row*PADK + sg*8] = *(const U4*)&A[(size_t)(m0+row)*512 + k0 + sg*8]; }
        #pragma unroll
        for (int s = 0; s < 2; ++s){ int q = tid + s*512; int row = q >> 2, sg = q & 3;
          *(U4*)&Bl[row*PADK + sg*8] = *(const U4*)&B[(size_t)(n0+row)*512 + k0 + sg*8]; }
        __syncthreads();
        mfma_tile(Al, Bl, acc, lane, wr, wc);
    }
    int cl = lane & 15, rg = (lane >> 4) * 4;
    #pragma unroll
    for (int mi=0; mi<4; ++mi){
        int rb = m0 + wr*64 + mi*16 + rg;
        #pragma unroll
        for (int ni=0; ni<4; ++ni){
            int col = n0 + wc*64 + ni*16 + cl;
            #pragma unroll
            for (int r=0;r<4;++r) pw[(size_t)p*262144 + (size_t)(rb+r)*512 + col] = f2b(acc[mi][ni][r]);
            if (p < 32){
                S4 pk; pk.x=f2b(acc[mi][ni][0]); pk.y=f2b(acc[mi][ni][1]); pk.z=f2b(acc[mi][ni][2]); pk.w=f2b(acc[mi][ni][3]);
                *(S4*)&pwT[(size_t)p*262144 + (size_t)col*512 + rb] = pk;
            }
        }
    }
}

// ---------------- ar_u: y = sum_i shift(u,i) @ M_u[i]^T ----------------
__global__ __launch_bounds__(512) void k_aru(const unsigned short* __restrict__ u,
                                             const unsigned short* __restrict__ Mu, float* __restrict__ y){
    GEMM_PROLOG
    int tt = blockIdx.x, b = blockIdx.y;
    int t0 = tt * BM;
    const unsigned short* Ab = u + (size_t)b*SLEN*DIM;
    for (int i = 0; i < 3; ++i){
        const unsigned short* Bsrc = Mu + (size_t)i*65536;
        for (int k0 = 0; k0 < 256; k0 += BKK){
            __syncthreads();
            { int row = tid >> 2, sg = tid & 3; int t = t0 + row - i;
              U4 val; val.a=val.b=val.c=val.d=0u;
              if (t >= 0) val = *(const U4*)&Ab[(size_t)t*DIM + k0 + sg*8];
              *(U4*)&Al[row*PADK + sg*8] = val; }
            #pragma unroll
            for (int s = 0; s < 2; ++s){ int q = tid + s*512; int row = q >> 2, sg = q & 3;
              *(U4*)&Bl[row*PADK + sg*8] = *(const U4*)&Bsrc[(size_t)row*DIM + k0 + sg*8]; }
            __syncthreads();
            mfma_tile(Al, Bl, acc, lane, wr, wc);
        }
    }
    int cl = lane & 15, rg = (lane >> 4) * 4;
    #pragma unroll
    for (int mi=0; mi<4; ++mi){
        int tb = t0 + wr*64 + mi*16 + rg;
        #pragma unroll
        for (int ni=0; ni<4; ++ni){
            int o = wc*64 + ni*16 + cl;
            #pragma unroll
            for (int r=0;r<4;++r) y[((size_t)b*SLEN + tb + r)*DIM + o] = acc[mi][ni][r];
        }
    }
}

// ---------------- projection: V[k][b][o][t] = sr_k * (alt_t) * (u @ Mk^T) ----------------
__global__ __launch_bounds__(512) void k_proj(const unsigned short* __restrict__ u,
                                              const unsigned short* __restrict__ Mb,
                                              const float* __restrict__ sigma,
                                              unsigned short* __restrict__ V, int minus){
    GEMM_PROLOG
    int tt = blockIdx.x, b = blockIdx.y, k = blockIdx.z;
    int t0 = tt * BM;
    float sr = powf(sigma[k], 0.25f);
    const unsigned short* Asrc = u + ((size_t)b*SLEN + t0)*DIM;
    const unsigned short* Bsrc = Mb + (size_t)k*65536;
    for (int k0 = 0; k0 < 256; k0 += BKK){
        __syncthreads();
        { int row = tid >> 2, sg = tid & 3;
          *(U4*)&Al[row*PADK + sg*8] = *(const U4*)&Asrc[(size_t)row*DIM + k0 + sg*8]; }
        #pragma unroll
        for (int s = 0; s < 2; ++s){ int q = tid + s*512; int row = q >> 2, sg = q & 3;
          *(U4*)&Bl[row*PADK + sg*8] = *(const U4*)&Bsrc[(size_t)row*DIM + k0 + sg*8]; }
        __syncthreads();
        mfma_tile(Al, Bl, acc, lane, wr, wc);
    }
    int cl = lane & 15, rg = (lane >> 4) * 4;
    #pragma unroll
    for (int mi=0; mi<4; ++mi){
        int tb = t0 + wr*64 + mi*16 + rg;
        #pragma unroll
        for (int ni=0; ni<4; ++ni){
            int o = wc*64 + ni*16 + cl;
            S4 pk;
            float s0 = (minus && ((tb+0)&1)) ? -sr : sr;
            float s1 = (minus && ((tb+1)&1)) ? -sr : sr;
            float s2 = (minus && ((tb+2)&1)) ? -sr : sr;
            float s3 = (minus && ((tb+3)&1)) ? -sr : sr;
            pk.x = f2b(acc[mi][ni][0]*s0); pk.y = f2b(acc[mi][ni][1]*s1);
            pk.z = f2b(acc[mi][ni][2]*s2); pk.w = f2b(acc[mi][ni][3]*s3);
            *(S4*)&V[(((size_t)k*NB + b)*DIM + o)*SLEN + tb] = pk;
        }
    }
}

// ---------------- causal Toeplitz conv v2 ----------------
// grid (72 pairs jx-major, NB, KG). Per block: 8 filters, phi windows in LDS
// (reversed, 4 shifted copies -> aligned b64 frag reads), V staged in
// 8B-chunk-XOR-swizzled Bl. acc += sum over kk, tau.
__global__ __launch_bounds__(512) void k_conv(const unsigned short* __restrict__ V,
                                              const unsigned short* __restrict__ phiT,
                                              float* __restrict__ y){
    __shared__ unsigned short phiC[KPB*PCOPY*PHIW];
    __shared__ unsigned short Bl[256*32];   // 64B rows, chunk-swizzled
    int tid = threadIdx.x, lane = tid & 63, wv = tid >> 6, wr = wv >> 2, wc = wv & 3;
    f32x4 acc[4][4];
    { f32x4 z = {0.f,0.f,0.f,0.f};
      for (int mi=0;mi<4;++mi) for (int ni=0;ni<4;++ni) acc[mi][ni] = z; }

    int px = blockIdx.x, b = blockIdx.y, kg = blockIdx.z;
    // jx-major triangle decode: group jx has 16-2*jx tiles (tt = 2*jx + rem)
    int jx = 0, rem = px;
    #pragma unroll
    for (int j = 0; j < 8; ++j){
        int c = 16 - 2*j;
        if (rem < c){ jx = j; break; }
        rem -= c;
    }
    int tt = 2*jx + rem;
    int t0 = tt*BM, tau0 = jx*256;
    int wb = t0 - tau0 - 255;   // window base (dl of phiR[383])

    // stage reversed phi windows: phiC[kk][p][i] = phi_k[wb + 383 - (i+p)]
    for (int idx = tid; idx < KPB*PCOPY*PHIW; idx += 512){
        int kk = idx / (PCOPY*PHIW);
        int r2 = idx - kk*(PCOPY*PHIW);
        int p = r2 / PHIW, i = r2 - p*PHIW;
        int dl = wb + 383 - (i + p);
        unsigned short vphi = 0;
        if (dl >= 0 && dl < SLEN) vphi = phiT[(size_t)(kg*KPB + kk)*SLEN + dl];
        phiC[idx] = vphi;
    }

    int cl = lane & 15, g = lane >> 4, kb = g*8;
    for (int kk = 0; kk < KPB; ++kk){
        const unsigned short* Vkb = V + (((size_t)(kg*KPB + kk)*NB + b)*DIM)*SLEN;
        const unsigned short* pcb = &phiC[kk*PCOPY*PHIW];
        for (int ssb = 0; ssb < 8; ++ssb){
            int ts = tau0 + ssb*BKK;
            __syncthreads();   // waves done reading previous Bl (also fences phiC on iter 0)
            #pragma unroll
            for (int s = 0; s < 2; ++s){
                int q = tid + s*512; int row = q >> 2, sg = q & 3;
                U4 val = *(const U4*)&Vkb[(size_t)row*SLEN + ts + sg*8];
                int r7 = row & 7;
                int dstc = ((sg*2) ^ r7) & ~1;
                U4 w = val;
                if (r7 & 1){ w.a = val.c; w.b = val.d; w.c = val.a; w.d = val.b; }
                *(U4*)&Bl[row*32 + dstc*4] = w;
            }
            __syncthreads();
            // A frags from phi window (aligned b64 pairs)
            bf16x8 a[4], bb[4];
            int base_s = 128 - (wr*64 + cl) + ssb*BKK + kb;
            int p = base_s & 3;
            const unsigned short* pc = pcb + p*PHIW;
            #pragma unroll
            for (int mi = 0; mi < 4; ++mi){
                int i0 = (base_s - mi*16) - p;
                bf16x4 lo = *(const bf16x4*)&pc[i0];
                bf16x4 hi = *(const bf16x4*)&pc[i0 + 4];
                a[mi] = __builtin_shufflevector(lo, hi, 0,1,2,3,4,5,6,7);
            }
            // B frags from swizzled Bl
            #pragma unroll
            for (int ni = 0; ni < 4; ++ni){
                int row = wc*64 + ni*16 + cl;
                int r7 = row & 7;
                const unsigned short* bp = &Bl[row*32];
                int c1 = (2*g) ^ r7;
                bf16x4 lo = *(const bf16x4*)&bp[c1*4];
                bf16x4 hi = *(const bf16x4*)&bp[(c1^1)*4];
                bb[ni] = __builtin_shufflevector(lo, hi, 0,1,2,3,4,5,6,7);
            }
            #pragma unroll
            for (int mi = 0; mi < 4; ++mi)
                #pragma unroll
                for (int ni = 0; ni < 4; ++ni)
                    acc[mi][ni] = __builtin_amdgcn_mfma_f32_16x16x32_bf16(a[mi], bb[ni], acc[mi][ni], 0, 0, 0);
        }
    }
    int rg = (lane >> 4) * 4;
    #pragma unroll
    for (int mi=0; mi<4; ++mi){
        int tb = t0 + wr*64 + mi*16 + rg;
        #pragma unroll
        for (int ni=0; ni<4; ++ni){
            int o = wc*64 + ni*16 + cl;
            #pragma unroll
            for (int r=0;r<4;++r) atomicAdd(&y[((size_t)b*SLEN + tb + r)*DIM + o], acc[mi][ni][r]);
        }
    }
}

// ---------------- output AR via truncated Q-filter: yhat += sum_{p>=1} Q_p y_{t-p} ----------------
__global__ __launch_bounds__(512) void k_qconv(const unsigned short* __restrict__ yb,
                                               const unsigned short* __restrict__ pw,
                                               float* __restrict__ yh){
    GEMM_PROLOG
    int tt = blockIdx.x, b = blockIdx.y, gz = blockIdx.z;
    int t0 = tt * BM;
    const unsigned short* ysrc = yb + (size_t)b*SLEN*DIM;
    for (int pi = 0; pi < 8; ++pi){
        int p = gz*8 + pi;
        if (p == 0) continue;
        const unsigned short* Q = pw + (size_t)p*262144;
        for (int k0 = 0; k0 < 256; k0 += BKK){
            __syncthreads();
            { int row = tid >> 2, sg = tid & 3; int t = t0 + row - p;
              U4 val; val.a=val.b=val.c=val.d=0u;
              if (t >= 0) val = *(const U4*)&ysrc[(size_t)t*DIM + k0 + sg*8];
              *(U4*)&Al[row*PADK + sg*8] = val; }
            #pragma unroll
            for (int s = 0; s < 2; ++s){ int q = tid + s*512; int row = q >> 2, sg = q & 3;
              *(U4*)&Bl[row*PADK + sg*8] = *(const U4*)&Q[(size_t)row*512 + k0 + sg*8]; }
            __syncthreads();
            mfma_tile(Al, Bl, acc, lane, wr, wc);
        }
    }
    int cl = lane & 15, rg = (lane >> 4) * 4;
    #pragma unroll
    for (int mi=0; mi<4; ++mi){
        int tb = t0 + wr*64 + mi*16 + rg;
        #pragma unroll
        for (int ni=0; ni<4; ++ni){
            int o = wc*64 + ni*16 + cl;
            #pragma unroll
            for (int r=0;r<4;++r) atomicAdd(&yh[((size_t)b*SLEN + tb + r)*DIM + o], acc[mi][ni][r]);
        }
    }
}

// ---------------- MLP GEMM1 (w1 and v fused over n-tiles), outputs transposed [h][bt] ----------------
__global__ __launch_bounds__(512) void k_mlp1(const unsigned short* __restrict__ hb,
                                              const unsigned short* __restrict__ w1T,
                                              const unsigned short* __restrict__ vT,
                                              unsigned short* __restrict__ h1T,
                                              unsigned short* __restrict__ gT){
    GEMM_PROLOG
    int tt = blockIdx.x, b = blockIdx.y, nt = blockIdx.z;
    int t0 = tt * BM;
    const unsigned short* Bsrc = (nt < 4) ? (w1T + (size_t)nt*256*256) : (vT + (size_t)(nt-4)*256*256);
    unsigned short* dst = (nt < 4) ? h1T : gT;
    int h0 = (nt & 3) * 256;
    const unsigned short* Asrc = hb + ((size_t)b*SLEN + t0)*DIM;
    for (int k0 = 0; k0 < 256; k0 += BKK){
        __syncthreads();
        { int row = tid >> 2, sg = tid & 3;
          *(U4*)&Al[row*PADK + sg*8] = *(const U4*)&Asrc[(size_t)row*DIM + k0 + sg*8]; }
        #pragma unroll
        for (int s = 0; s < 2; ++s){ int q = tid + s*512; int row = q >> 2, sg = q & 3;
          *(U4*)&Bl[row*PADK + sg*8] = *(const U4*)&Bsrc[(size_t)row*DIM + k0 + sg*8]; }
        __syncthreads();
        mfma_tile(Al, Bl, acc, lane, wr, wc);
    }
    int cl = lane & 15, rg = (lane >> 4) * 4;
    #pragma unroll
    for (int mi=0; mi<4; ++mi){
        int btb = b*SLEN + t0 + wr*64 + mi*16 + rg;
        #pragma unroll
        for (int ni=0; ni<4; ++ni){
            int hcol = h0 + wc*64 + ni*16 + cl;
            S4 pk;
            pk.x = f2b(acc[mi][ni][0]); pk.y = f2b(acc[mi][ni][1]);
            pk.z = f2b(acc[mi][ni][2]); pk.w = f2b(acc[mi][ni][3]);
            *(S4*)&dst[(size_t)hcol*NROW + btb] = pk;
        }
    }
}

// ---------------- MLP GEMM2: out += act @ w2 (K split, A transpose-staged from actT) ----------------
__global__ __launch_bounds__(512) void k_mlp2(const unsigned short* __restrict__ actT,
                                              const unsigned short* __restrict__ w2T,
                                              float* __restrict__ out){
    GEMM_PROLOG
    int tt = blockIdx.x, b = blockIdx.y, ks = blockIdx.z;
    int t0 = tt * BM;
    int bt0 = b*SLEN + t0;
    for (int k0 = ks*256; k0 < ks*256 + 256; k0 += BKK){
        __syncthreads();
        { int hj = tid & 31, tsg = tid >> 5;
          const unsigned short* src = &actT[(size_t)(k0 + hj)*NROW + bt0 + tsg*8];
          union { U4 v; unsigned short s[8]; } pk;
          pk.v = *(const U4*)src;
          #pragma unroll
          for (int e = 0; e < 8; ++e) Al[(tsg*8 + e)*PADK + hj] = pk.s[e];
        }
        #pragma unroll
        for (int s = 0; s < 2; ++s){ int q = tid + s*512; int row = q >> 2, sg = q & 3;
          *(U4*)&Bl[row*PADK + sg*8] = *(const U4*)&w2T[(size_t)row*NH + k0 + sg*8]; }
        __syncthreads();
        mfma_tile(Al, Bl, acc, lane, wr, wc);
    }
    int cl = lane & 15, rg = (lane >> 4) * 4;
    #pragma unroll
    for (int mi=0; mi<4; ++mi){
        int tb = t0 + wr*64 + mi*16 + rg;
        #pragma unroll
        for (int ni=0; ni<4; ++ni){
            int o = wc*64 + ni*16 + cl;
            #pragma unroll
            for (int r=0;r<4;++r) atomicAdd(&out[((size_t)b*SLEN + tb + r)*DIM + o], acc[mi][ni][r]);
        }
    }
}

// ---------------- host ----------------

extern "C" void kernel_launch(void* const* d_in, const int* in_sizes, int n_in,
                              void* d_out, int out_size, void* d_ws, size_t ws_size,
                              hipStream_t stream) {
    (void)in_sizes; (void)n_in; (void)out_size;
    const float* x     = (const float*)d_in[0];
    const float* sigma = (const float*)d_in[1];
    const float* phi   = (const float*)d_in[2];
    const float* rmsw  = (const float*)d_in[3];
    const float* Mu    = (const float*)d_in[4];
    const float* Mp    = (const float*)d_in[5];
    const float* Mm    = (const float*)d_in[6];
    const float* my    = (const float*)d_in[7];
    const float* w1    = (const float*)d_in[8];
    const float* vv    = (const float*)d_in[9];
    const float* w2    = (const float*)d_in[10];
    float* out = (float*)d_out;

    char* ws = (char*)d_ws;
    size_t off = 0;
    auto alloc = [&](size_t bytes){ size_t o = off; off += (bytes + 255) & ~(size_t)255; return o; };

    size_t o_u    = alloc((size_t)NROW*DIM*2);
    size_t o_phiT = alloc((size_t)NKF*SLEN*2);
    size_t o_MuB  = alloc((size_t)3*65536*2);
    size_t o_MpB  = alloc((size_t)NKF*65536*2);
    size_t o_MmB  = alloc((size_t)NKF*65536*2);
    size_t o_w1T  = alloc((size_t)NH*DIM*2);
    size_t o_vT   = alloc((size_t)NH*DIM*2);
    size_t o_w2T  = alloc((size_t)DIM*NH*2);
    size_t o_pow  = alloc((size_t)64*512*512*2);
    size_t o_powT = alloc((size_t)32*512*512*2);
    size_t o_V    = alloc((size_t)NKF*NB*DIM*SLEN*2);
    size_t o_y    = alloc((size_t)NTOT*4);
    size_t o_yhat = alloc((size_t)NTOT*4);
    size_t o_ybf  = alloc((size_t)NTOT*2);
    size_t o_yhbf = alloc((size_t)NTOT*2);
    size_t o_h1T  = alloc((size_t)NH*NROW*2);
    size_t o_gT   = alloc((size_t)NH*NROW*2);
    size_t o_actT = alloc((size_t)NH*NROW*2);
    if (off > ws_size) return;

    unsigned short* u_b  = (unsigned short*)(ws + o_u);
    unsigned short* phiT = (unsigned short*)(ws + o_phiT);
    unsigned short* MuB  = (unsigned short*)(ws + o_MuB);
    unsigned short* MpB  = (unsigned short*)(ws + o_MpB);
    unsigned short* MmB  = (unsigned short*)(ws + o_MmB);
    unsigned short* w1T  = (unsigned short*)(ws + o_w1T);
    unsigned short* vT   = (unsigned short*)(ws + o_vT);
    unsigned short* w2T  = (unsigned short*)(ws + o_w2T);
    unsigned short* pw   = (unsigned short*)(ws + o_pow);
    unsigned short* pwT  = (unsigned short*)(ws + o_powT);
    unsigned short* V    = (unsigned short*)(ws + o_V);
    float* y     = (float*)(ws + o_y);
    float* yhat  = (float*)(ws + o_yhat);
    unsigned short* ybf  = (unsigned short*)(ws + o_ybf);
    unsigned short* yhbf = (unsigned short*)(ws + o_yhbf);
    unsigned short* h1T  = (unsigned short*)(ws + o_h1T);
    unsigned short* gT   = (unsigned short*)(ws + o_gT);
    unsigned short* actT = (unsigned short*)(ws + o_actT);

    // weight conversions
    k_cast4<<<dim3(3*65536/4/256), 256, 0, stream>>>((const float4*)Mu, (S4*)MuB, 3*65536/4);
    k_cast4<<<dim3(NKF*65536/4/256), 256, 0, stream>>>((const float4*)Mp, (S4*)MpB, NKF*65536/4);
    k_cast4<<<dim3(NKF*65536/4/256), 256, 0, stream>>>((const float4*)Mm, (S4*)MmB, NKF*65536/4);
    k_transpose<<<dim3((SLEN*NKF+255)/256), 256, 0, stream>>>(phi, phiT, SLEN, NKF);
    k_transpose<<<dim3((DIM*NH+255)/256), 256, 0, stream>>>(w1, w1T, DIM, NH);
    k_transpose<<<dim3((DIM*NH+255)/256), 256, 0, stream>>>(vv, vT, DIM, NH);
    k_transpose<<<dim3((NH*DIM+255)/256), 256, 0, stream>>>(w2, w2T, NH, DIM);
    k_buildM<<<dim3(1024), 256, 0, stream>>>(my, pw, pwT);

    // rmsnorm
    k_rmsnorm<<<dim3(NROW), 256, 0, stream>>>(x, rmsw, u_b);

    // companion-matrix powers via doubling (bf16, f32 accumulate)
    const int ns[6]   = {1, 2, 4, 8, 16, 32};
    const int cnts[6] = {1, 2, 4, 8, 16, 31};
    for (int s = 0; s < 6; ++s)
        k_pow<<<dim3(4, 2, cnts[s]), 512, 0, stream>>>(pw, pwT, ns[s], 1);

    // y = ar_u
    k_aru<<<dim3(16, NB), 512, 0, stream>>>(u_b, MuB, y);

    // spectral: two passes (plus, minus) reusing V
    for (int pm = 0; pm < 2; ++pm){
        k_proj<<<dim3(16, NB, NKF), 512, 0, stream>>>(u_b, pm ? MmB : MpB, sigma, V, pm);
        k_conv<<<dim3(72, NB, KG), 512, 0, stream>>>(V, phiT, y);
    }

    // output AR recurrence via truncated Q-filter (P=64)
    k_yinit<<<dim3(NTOT/4/256), 256, 0, stream>>>((const float4*)y, (float4*)yhat, (S4*)ybf);
    k_qconv<<<dim3(16, NB, 8), 512, 0, stream>>>(ybf, pw, yhat);
    k_cast4<<<dim3(NTOT/4/256), 256, 0, stream>>>((const float4*)yhat, (S4*)yhbf, NTOT/4);

    // MLP + residuals
    k_mlp1<<<dim3(16, NB, 8), 512, 0, stream>>>(yhbf, w1T, vT, h1T, gT);
    k_act<<<dim3(NH*NROW/8/256), 256, 0, stream>>>((const U4*)h1T, (const U4*)gT, (U4*)actT);
    k_outinit<<<dim3(NTOT/4/256), 256, 0, stream>>>((const float4*)x, (const float4*)yhat, (float4*)out);
    k_mlp2<<<dim3(16, NB, 4), 512, 0, stream>>>(actT, w2T, out);
}

// Round 3
// 962.655 us; speedup vs baseline: 1.5125x; 1.0971x over previous
//
#include <hip/hip_runtime.h>
#include <hip/hip_bf16.h>
#include <math.h>

#define SLEN 2048
#define DIM 256
#define NB 4
#define NKF 24
#define NH 1024
#define NROW (NB*SLEN)          // 8192
#define NTOT (NB*SLEN*DIM)      // 2097152

#define BM 128
#define BN 256
#define BKK 32
#define PADK 40                 // padded LDS row stride (bf16 elems); conflict-free for U4 stage + b128 frag reads

#define KG 3                    // conv k-group blocks
#define KPB 8                   // filters per conv block
#define VELEMS ((size_t)NKF*NB*DIM*SLEN)   // one V buffer (plus or minus): 50,331,648 elems

typedef __attribute__((ext_vector_type(8))) short bf16x8;
typedef __attribute__((ext_vector_type(4))) float f32x4;

struct __align__(16) U4 { unsigned int a, b, c, d; };
struct __align__(8)  S4 { unsigned short x, y, z, w; };

__device__ __forceinline__ unsigned short f2b(float v){
    union { __hip_bfloat16 h; unsigned short u; } cv;
    cv.h = __float2bfloat16(v);
    return cv.u;
}
__device__ __forceinline__ float b2f(unsigned short s){
    union { __hip_bfloat16 h; unsigned short u; } cv;
    cv.u = s;
    return __bfloat162float(cv.h);
}

// ---------------- small elementwise kernels ----------------

__global__ void k_cast4(const float4* __restrict__ src, S4* __restrict__ dst, int n4){
    int i = blockIdx.x*256 + threadIdx.x;
    if (i < n4){
        float4 v = src[i];
        S4 p; p.x = f2b(v.x); p.y = f2b(v.y); p.z = f2b(v.z); p.w = f2b(v.w);
        dst[i] = p;
    }
}

__global__ void k_transpose(const float* __restrict__ src, unsigned short* __restrict__ dst, int R, int C){
    int i = blockIdx.x*256 + threadIdx.x;
    if (i < R*C){ int r = i / C, c = i - r*C; dst[(size_t)c*R + r] = f2b(src[i]); }
}

// Toeplitz tiles: T[k][rem][r][c] = phi_k[rem*128 + r - c], 24*16 tiles of 128x256
__global__ void k_toep(const unsigned short* __restrict__ phiT, unsigned short* __restrict__ T){
    int i = blockIdx.x*256 + threadIdx.x;       // 0 .. 24*16*128*64-1
    if (i >= NKF*16*128*64) return;
    int c4 = (i & 63) * 4;
    int r  = (i >> 6) & 127;
    int rem= (i >> 13) & 15;
    int k  = i >> 17;
    int d0 = rem*128 + r - c4;                  // max 2047, fits phi
    const unsigned short* pk = phiT + (size_t)k*SLEN;
    S4 p;
    p.x = (d0   >= 0) ? pk[d0]   : (unsigned short)0;
    p.y = (d0-1 >= 0) ? pk[d0-1] : (unsigned short)0;
    p.z = (d0-2 >= 0) ? pk[d0-2] : (unsigned short)0;
    p.w = (d0-3 >= 0) ? pk[d0-3] : (unsigned short)0;
    *(S4*)&T[(size_t)i*4] = p;
}

// build M = [[A1, A2],[I, 0]] into pow[1] (row-major) and powT[1] (transposed)
__global__ void k_buildM(const float* __restrict__ my, unsigned short* __restrict__ pw, unsigned short* __restrict__ pwT){
    int i = blockIdx.x*256 + threadIdx.x;
    if (i >= 512*512) return;
    int r = i >> 9, c = i & 511;
    float v;
    if (r < 256) v = (c < 256) ? my[r*256 + c] : my[256*256 + r*256 + (c - 256)];
    else         v = (c == r - 256) ? 1.0f : 0.0f;
    unsigned short bb = f2b(v);
    pw [262144 + (size_t)r*512 + c] = bb;
    pwT[262144 + (size_t)c*512 + r] = bb;
}

__global__ void k_rmsnorm(const float* __restrict__ x, const float* __restrict__ w, unsigned short* __restrict__ u){
    int row = blockIdx.x;
    int t = threadIdx.x;
    float v = x[(size_t)row*DIM + t];
    float ss = v*v;
    #pragma unroll
    for (int o = 32; o > 0; o >>= 1) ss += __shfl_down(ss, o, 64);
    __shared__ float red[4];
    if ((t & 63) == 0) red[t >> 6] = ss;
    __syncthreads();
    float tot = red[0]+red[1]+red[2]+red[3];
    float sc = rsqrtf(tot * (1.0f/256.0f) + 1e-6f);
    u[(size_t)row*DIM + t] = f2b(v * sc * w[t]);
}

__global__ void k_yinit(const float4* __restrict__ y, float4* __restrict__ yh, S4* __restrict__ yb){
    int i = blockIdx.x*256 + threadIdx.x;
    if (i < NTOT/4){
        float4 v = y[i];
        yh[i] = v;
        S4 p; p.x = f2b(v.x); p.y = f2b(v.y); p.z = f2b(v.z); p.w = f2b(v.w);
        yb[i] = p;
    }
}

__global__ void k_act(const U4* __restrict__ h1T, const U4* __restrict__ gT, U4* __restrict__ actT){
    int i = blockIdx.x*256 + threadIdx.x;
    if (i < NH*NROW/8){
        union { U4 v; unsigned short s[8]; } a, g, r;
        a.v = h1T[i]; g.v = gT[i];
        #pragma unroll
        for (int e = 0; e < 8; ++e){
            float av = b2f(a.s[e]);
            float gv = b2f(g.s[e]);
            float sv = av / (1.0f + expf(-av));
            r.s[e] = f2b(sv * gv);
        }
        actT[i] = r.v;
    }
}

__global__ void k_outinit(const float4* __restrict__ x, const float4* __restrict__ yh, float4* __restrict__ out){
    int i = blockIdx.x*256 + threadIdx.x;
    if (i < NTOT/4){
        float4 a = x[i], b = yh[i];
        float4 r; r.x = a.x+b.x; r.y = a.y+b.y; r.z = a.z+b.z; r.w = a.w+b.w;
        out[i] = r;
    }
}

// ---------------- shared MFMA tile core ----------------
// 128x256 tile, 8 waves (2x4), each wave 64x64 = 4x4 frags of 16x16, K-step 32.

__device__ __forceinline__ void mfma_tile(const unsigned short* Al, const unsigned short* Bl,
                                          f32x4 acc[4][4], int lane, int wr, int wc){
    int cl = lane & 15;
    int kb = (lane >> 4) * 8;
    bf16x8 a[4], b[4];
    #pragma unroll
    for (int mi = 0; mi < 4; ++mi)
        a[mi] = *(const bf16x8*)&Al[(wr*64 + mi*16 + cl)*PADK + kb];
    #pragma unroll
    for (int ni = 0; ni < 4; ++ni)
        b[ni] = *(const bf16x8*)&Bl[(wc*64 + ni*16 + cl)*PADK + kb];
    #pragma unroll
    for (int mi = 0; mi < 4; ++mi)
        #pragma unroll
        for (int ni = 0; ni < 4; ++ni)
            acc[mi][ni] = __builtin_amdgcn_mfma_f32_16x16x32_bf16(a[mi], b[ni], acc[mi][ni], 0, 0, 0);
}

#define GEMM_PROLOG \
    __shared__ unsigned short Al[BM*PADK]; \
    __shared__ unsigned short Bl[BN*PADK]; \
    int tid = threadIdx.x, lane = tid & 63, wv = tid >> 6, wr = wv >> 2, wc = wv & 3; \
    f32x4 acc[4][4]; \
    { f32x4 z = {0.f,0.f,0.f,0.f}; \
      for (int mi=0;mi<4;++mi) for (int ni=0;ni<4;++ni) acc[mi][ni] = z; }

// ---------------- batched power doubling: pow[n+j] = pow[n] * pow[j] ----------------
__global__ __launch_bounds__(512) void k_pow(unsigned short* __restrict__ pw, unsigned short* __restrict__ pwT,
                                             int n, int jbase){
    GEMM_PROLOG
    int mt = blockIdx.x, nt = blockIdx.y;
    int j = jbase + blockIdx.z;
    int p = n + j;
    const unsigned short* A = pw  + (size_t)n * 262144;
    const unsigned short* B = pwT + (size_t)j * 262144;
    int m0 = mt * BM, n0 = nt * BN;
    for (int k0 = 0; k0 < 512; k0 += BKK){
        __syncthreads();
        { int row = tid >> 2, sg = tid & 3;
          *(U4*)&Al[row*PADK + sg*8] = *(const U4*)&A[(size_t)(m0+row)*512 + k0 + sg*8]; }
        #pragma unroll
        for (int s = 0; s < 2; ++s){ int q = tid + s*512; int row = q >> 2, sg = q & 3;
          *(U4*)&Bl[row*PADK + sg*8] = *(const U4*)&B[(size_t)(n0+row)*512 + k0 + sg*8]; }
        __syncthreads();
        mfma_tile(Al, Bl, acc, lane, wr, wc);
    }
    int cl = lane & 15, rg = (lane >> 4) * 4;
    #pragma unroll
    for (int mi=0; mi<4; ++mi){
        int rb = m0 + wr*64 + mi*16 + rg;
        #pragma unroll
        for (int ni=0; ni<4; ++ni){
            int col = n0 + wc*64 + ni*16 + cl;
            #pragma unroll
            for (int r=0;r<4;++r) pw[(size_t)p*262144 + (size_t)(rb+r)*512 + col] = f2b(acc[mi][ni][r]);
            if (p < 32){
                S4 pk; pk.x=f2b(acc[mi][ni][0]); pk.y=f2b(acc[mi][ni][1]); pk.z=f2b(acc[mi][ni][2]); pk.w=f2b(acc[mi][ni][3]);
                *(S4*)&pwT[(size_t)p*262144 + (size_t)col*512 + rb] = pk;
            }
        }
    }
}

// ---------------- ar_u: y = sum_i shift(u,i) @ M_u[i]^T ----------------
__global__ __launch_bounds__(512) void k_aru(const unsigned short* __restrict__ u,
                                             const unsigned short* __restrict__ Mu, float* __restrict__ y){
    GEMM_PROLOG
    int tt = blockIdx.x, b = blockIdx.y;
    int t0 = tt * BM;
    const unsigned short* Ab = u + (size_t)b*SLEN*DIM;
    for (int i = 0; i < 3; ++i){
        const unsigned short* Bsrc = Mu + (size_t)i*65536;
        for (int k0 = 0; k0 < 256; k0 += BKK){
            __syncthreads();
            { int row = tid >> 2, sg = tid & 3; int t = t0 + row - i;
              U4 val; val.a=val.b=val.c=val.d=0u;
              if (t >= 0) val = *(const U4*)&Ab[(size_t)t*DIM + k0 + sg*8];
              *(U4*)&Al[row*PADK + sg*8] = val; }
            #pragma unroll
            for (int s = 0; s < 2; ++s){ int q = tid + s*512; int row = q >> 2, sg = q & 3;
              *(U4*)&Bl[row*PADK + sg*8] = *(const U4*)&Bsrc[(size_t)row*DIM + k0 + sg*8]; }
            __syncthreads();
            mfma_tile(Al, Bl, acc, lane, wr, wc);
        }
    }
    int cl = lane & 15, rg = (lane >> 4) * 4;
    #pragma unroll
    for (int mi=0; mi<4; ++mi){
        int tb = t0 + wr*64 + mi*16 + rg;
        #pragma unroll
        for (int ni=0; ni<4; ++ni){
            int o = wc*64 + ni*16 + cl;
            #pragma unroll
            for (int r=0;r<4;++r) y[((size_t)b*SLEN + tb + r)*DIM + o] = acc[mi][ni][r];
        }
    }
}

// ---------------- projection: V[k][b][o][t] = sr_k * (alt_t) * (u @ Mk^T) ----------------
__global__ __launch_bounds__(512) void k_proj(const unsigned short* __restrict__ u,
                                              const unsigned short* __restrict__ Mb,
                                              const float* __restrict__ sigma,
                                              unsigned short* __restrict__ V, int minus){
    GEMM_PROLOG
    int tt = blockIdx.x, b = blockIdx.y, k = blockIdx.z;
    int t0 = tt * BM;
    float sr = powf(sigma[k], 0.25f);
    const unsigned short* Asrc = u + ((size_t)b*SLEN + t0)*DIM;
    const unsigned short* Bsrc = Mb + (size_t)k*65536;
    for (int k0 = 0; k0 < 256; k0 += BKK){
        __syncthreads();
        { int row = tid >> 2, sg = tid & 3;
          *(U4*)&Al[row*PADK + sg*8] = *(const U4*)&Asrc[(size_t)row*DIM + k0 + sg*8]; }
        #pragma unroll
        for (int s = 0; s < 2; ++s){ int q = tid + s*512; int row = q >> 2, sg = q & 3;
          *(U4*)&Bl[row*PADK + sg*8] = *(const U4*)&Bsrc[(size_t)row*DIM + k0 + sg*8]; }
        __syncthreads();
        mfma_tile(Al, Bl, acc, lane, wr, wc);
    }
    int cl = lane & 15, rg = (lane >> 4) * 4;
    #pragma unroll
    for (int mi=0; mi<4; ++mi){
        int tb = t0 + wr*64 + mi*16 + rg;
        #pragma unroll
        for (int ni=0; ni<4; ++ni){
            int o = wc*64 + ni*16 + cl;
            S4 pk;
            float s0 = (minus && ((tb+0)&1)) ? -sr : sr;
            float s1 = (minus && ((tb+1)&1)) ? -sr : sr;
            float s2 = (minus && ((tb+2)&1)) ? -sr : sr;
            float s3 = (minus && ((tb+3)&1)) ? -sr : sr;
            pk.x = f2b(acc[mi][ni][0]*s0); pk.y = f2b(acc[mi][ni][1]*s1);
            pk.z = f2b(acc[mi][ni][2]*s2); pk.w = f2b(acc[mi][ni][3]*s3);
            *(S4*)&V[(((size_t)k*NB + b)*DIM + o)*SLEN + tb] = pk;
        }
    }
}

// ---------------- causal Toeplitz conv v3: standard GEMM from precomputed T tiles ----------------
// grid (72 jx-major pairs, NB, KG). A = T[k][rem] (global), B = V rows; K per filter = pmcount*256
// (plus half then minus half), both accumulate into the same acc.
__global__ __launch_bounds__(512) void k_conv(const unsigned short* __restrict__ V,
                                              const unsigned short* __restrict__ Tt,
                                              float* __restrict__ y, int pmcount){
    GEMM_PROLOG
    int px = blockIdx.x, b = blockIdx.y, kg = blockIdx.z;
    int jx = 0, rem = px;
    #pragma unroll
    for (int j = 0; j < 8; ++j){
        int c = 16 - 2*j;
        if (rem < c){ jx = j; break; }
        rem -= c;
    }
    int tt = 2*jx + rem;
    int t0 = tt*BM, tau0 = jx*256;
    int KE = pmcount << 8;
    for (int kk = 0; kk < KPB; ++kk){
        int k = kg*KPB + kk;
        const unsigned short* Asrc = Tt + (size_t)(k*16 + rem)*128*256;
        const unsigned short* Vk   = V + (((size_t)k*NB + b)*DIM)*SLEN + tau0;
        for (int k0 = 0; k0 < KE; k0 += BKK){
            int kc = k0 & 255;
            const unsigned short* Bsrc = Vk + (size_t)(k0 >> 8)*VELEMS + kc;
            __syncthreads();
            { int row = tid >> 2, sg = tid & 3;
              *(U4*)&Al[row*PADK + sg*8] = *(const U4*)&Asrc[(size_t)row*256 + kc + sg*8]; }
            #pragma unroll
            for (int s = 0; s < 2; ++s){ int q = tid + s*512; int row = q >> 2, sg = q & 3;
              *(U4*)&Bl[row*PADK + sg*8] = *(const U4*)&Bsrc[(size_t)row*SLEN + sg*8]; }
            __syncthreads();
            mfma_tile(Al, Bl, acc, lane, wr, wc);
        }
    }
    int cl = lane & 15, rg = (lane >> 4) * 4;
    #pragma unroll
    for (int mi=0; mi<4; ++mi){
        int tb = t0 + wr*64 + mi*16 + rg;
        #pragma unroll
        for (int ni=0; ni<4; ++ni){
            int o = wc*64 + ni*16 + cl;
            #pragma unroll
            for (int r=0;r<4;++r) atomicAdd(&y[((size_t)b*SLEN + tb + r)*DIM + o], acc[mi][ni][r]);
        }
    }
}

// ---------------- output AR via truncated Q-filter: yhat += sum_{p>=1} Q_p y_{t-p} ----------------
__global__ __launch_bounds__(512) void k_qconv(const unsigned short* __restrict__ yb,
                                               const unsigned short* __restrict__ pw,
                                               float* __restrict__ yh){
    GEMM_PROLOG
    int tt = blockIdx.x, b = blockIdx.y, gz = blockIdx.z;
    int t0 = tt * BM;
    const unsigned short* ysrc = yb + (size_t)b*SLEN*DIM;
    for (int pi = 0; pi < 8; ++pi){
        int p = gz*8 + pi;
        if (p == 0) continue;
        const unsigned short* Q = pw + (size_t)p*262144;
        for (int k0 = 0; k0 < 256; k0 += BKK){
            __syncthreads();
            { int row = tid >> 2, sg = tid & 3; int t = t0 + row - p;
              U4 val; val.a=val.b=val.c=val.d=0u;
              if (t >= 0) val = *(const U4*)&ysrc[(size_t)t*DIM + k0 + sg*8];
              *(U4*)&Al[row*PADK + sg*8] = val; }
            #pragma unroll
            for (int s = 0; s < 2; ++s){ int q = tid + s*512; int row = q >> 2, sg = q & 3;
              *(U4*)&Bl[row*PADK + sg*8] = *(const U4*)&Q[(size_t)row*512 + k0 + sg*8]; }
            __syncthreads();
            mfma_tile(Al, Bl, acc, lane, wr, wc);
        }
    }
    int cl = lane & 15, rg = (lane >> 4) * 4;
    #pragma unroll
    for (int mi=0; mi<4; ++mi){
        int tb = t0 + wr*64 + mi*16 + rg;
        #pragma unroll
        for (int ni=0; ni<4; ++ni){
            int o = wc*64 + ni*16 + cl;
            #pragma unroll
            for (int r=0;r<4;++r) atomicAdd(&yh[((size_t)b*SLEN + tb + r)*DIM + o], acc[mi][ni][r]);
        }
    }
}

// ---------------- MLP GEMM1 (w1 and v fused over n-tiles), outputs transposed [h][bt] ----------------
__global__ __launch_bounds__(512) void k_mlp1(const unsigned short* __restrict__ hb,
                                              const unsigned short* __restrict__ w1T,
                                              const unsigned short* __restrict__ vT,
                                              unsigned short* __restrict__ h1T,
                                              unsigned short* __restrict__ gT){
    GEMM_PROLOG
    int tt = blockIdx.x, b = blockIdx.y, nt = blockIdx.z;
    int t0 = tt * BM;
    const unsigned short* Bsrc = (nt < 4) ? (w1T + (size_t)nt*256*256) : (vT + (size_t)(nt-4)*256*256);
    unsigned short* dst = (nt < 4) ? h1T : gT;
    int h0 = (nt & 3) * 256;
    const unsigned short* Asrc = hb + ((size_t)b*SLEN + t0)*DIM;
    for (int k0 = 0; k0 < 256; k0 += BKK){
        __syncthreads();
        { int row = tid >> 2, sg = tid & 3;
          *(U4*)&Al[row*PADK + sg*8] = *(const U4*)&Asrc[(size_t)row*DIM + k0 + sg*8]; }
        #pragma unroll
        for (int s = 0; s < 2; ++s){ int q = tid + s*512; int row = q >> 2, sg = q & 3;
          *(U4*)&Bl[row*PADK + sg*8] = *(const U4*)&Bsrc[(size_t)row*DIM + k0 + sg*8]; }
        __syncthreads();
        mfma_tile(Al, Bl, acc, lane, wr, wc);
    }
    int cl = lane & 15, rg = (lane >> 4) * 4;
    #pragma unroll
    for (int mi=0; mi<4; ++mi){
        int btb = b*SLEN + t0 + wr*64 + mi*16 + rg;
        #pragma unroll
        for (int ni=0; ni<4; ++ni){
            int hcol = h0 + wc*64 + ni*16 + cl;
            S4 pk;
            pk.x = f2b(acc[mi][ni][0]); pk.y = f2b(acc[mi][ni][1]);
            pk.z = f2b(acc[mi][ni][2]); pk.w = f2b(acc[mi][ni][3]);
            *(S4*)&dst[(size_t)hcol*NROW + btb] = pk;
        }
    }
}

// ---------------- MLP GEMM2: out += act @ w2 (K split, A transpose-staged from actT) ----------------
__global__ __launch_bounds__(512) void k_mlp2(const unsigned short* __restrict__ actT,
                                              const unsigned short* __restrict__ w2T,
                                              float* __restrict__ out){
    GEMM_PROLOG
    int tt = blockIdx.x, b = blockIdx.y, ks = blockIdx.z;
    int t0 = tt * BM;
    int bt0 = b*SLEN + t0;
    for (int k0 = ks*256; k0 < ks*256 + 256; k0 += BKK){
        __syncthreads();
        { int hj = tid & 31, tsg = tid >> 5;
          const unsigned short* src = &actT[(size_t)(k0 + hj)*NROW + bt0 + tsg*8];
          union { U4 v; unsigned short s[8]; } pk;
          pk.v = *(const U4*)src;
          #pragma unroll
          for (int e = 0; e < 8; ++e) Al[(tsg*8 + e)*PADK + hj] = pk.s[e];
        }
        #pragma unroll
        for (int s = 0; s < 2; ++s){ int q = tid + s*512; int row = q >> 2, sg = q & 3;
          *(U4*)&Bl[row*PADK + sg*8] = *(const U4*)&w2T[(size_t)row*NH + k0 + sg*8]; }
        __syncthreads();
        mfma_tile(Al, Bl, acc, lane, wr, wc);
    }
    int cl = lane & 15, rg = (lane >> 4) * 4;
    #pragma unroll
    for (int mi=0; mi<4; ++mi){
        int tb = t0 + wr*64 + mi*16 + rg;
        #pragma unroll
        for (int ni=0; ni<4; ++ni){
            int o = wc*64 + ni*16 + cl;
            #pragma unroll
            for (int r=0;r<4;++r) atomicAdd(&out[((size_t)b*SLEN + tb + r)*DIM + o], acc[mi][ni][r]);
        }
    }
}

// ---------------- host ----------------

extern "C" void kernel_launch(void* const* d_in, const int* in_sizes, int n_in,
                              void* d_out, int out_size, void* d_ws, size_t ws_size,
                              hipStream_t stream) {
    (void)in_sizes; (void)n_in; (void)out_size;
    const float* x     = (const float*)d_in[0];
    const float* sigma = (const float*)d_in[1];
    const float* phi   = (const float*)d_in[2];
    const float* rmsw  = (const float*)d_in[3];
    const float* Mu    = (const float*)d_in[4];
    const float* Mp    = (const float*)d_in[5];
    const float* Mm    = (const float*)d_in[6];
    const float* my    = (const float*)d_in[7];
    const float* w1    = (const float*)d_in[8];
    const float* vv    = (const float*)d_in[9];
    const float* w2    = (const float*)d_in[10];
    float* out = (float*)d_out;

    char* ws = (char*)d_ws;
    size_t off = 0;
    auto alloc = [&](size_t bytes){ size_t o = off; off += (bytes + 255) & ~(size_t)255; return o; };

    size_t o_u    = alloc((size_t)NROW*DIM*2);
    size_t o_phiT = alloc((size_t)NKF*SLEN*2);
    size_t o_T    = alloc((size_t)NKF*16*128*256*2);
    size_t o_MuB  = alloc((size_t)3*65536*2);
    size_t o_MpB  = alloc((size_t)NKF*65536*2);
    size_t o_MmB  = alloc((size_t)NKF*65536*2);
    size_t o_w1T  = alloc((size_t)NH*DIM*2);
    size_t o_vT   = alloc((size_t)NH*DIM*2);
    size_t o_w2T  = alloc((size_t)DIM*NH*2);
    size_t o_pow  = alloc((size_t)64*512*512*2);
    size_t o_powT = alloc((size_t)32*512*512*2);
    size_t o_y    = alloc((size_t)NTOT*4);
    size_t o_yhat = alloc((size_t)NTOT*4);
    size_t o_ybf  = alloc((size_t)NTOT*2);
    size_t o_yhbf = alloc((size_t)NTOT*2);
    size_t o_h1T  = alloc((size_t)NH*NROW*2);
    size_t o_gT   = alloc((size_t)NH*NROW*2);
    size_t o_actT = alloc((size_t)NH*NROW*2);
    size_t o_V    = alloc(VELEMS*2);            // at least one V buffer
    if (off > ws_size) return;
    // second V buffer (minus) if workspace allows -> merged single conv dispatch
    int pmcount = 1;
    if (off + VELEMS*2 <= ws_size){ pmcount = 2; }

    unsigned short* u_b  = (unsigned short*)(ws + o_u);
    unsigned short* phiT = (unsigned short*)(ws + o_phiT);
    unsigned short* Tt   = (unsigned short*)(ws + o_T);
    unsigned short* MuB  = (unsigned short*)(ws + o_MuB);
    unsigned short* MpB  = (unsigned short*)(ws + o_MpB);
    unsigned short* MmB  = (unsigned short*)(ws + o_MmB);
    unsigned short* w1T  = (unsigned short*)(ws + o_w1T);
    unsigned short* vT   = (unsigned short*)(ws + o_vT);
    unsigned short* w2T  = (unsigned short*)(ws + o_w2T);
    unsigned short* pw   = (unsigned short*)(ws + o_pow);
    unsigned short* pwT  = (unsigned short*)(ws + o_powT);
    unsigned short* V    = (unsigned short*)(ws + o_V);
    float* y     = (float*)(ws + o_y);
    float* yhat  = (float*)(ws + o_yhat);
    unsigned short* ybf  = (unsigned short*)(ws + o_ybf);
    unsigned short* yhbf = (unsigned short*)(ws + o_yhbf);
    unsigned short* h1T  = (unsigned short*)(ws + o_h1T);
    unsigned short* gT   = (unsigned short*)(ws + o_gT);
    unsigned short* actT = (unsigned short*)(ws + o_actT);

    // weight conversions
    k_cast4<<<dim3(3*65536/4/256), 256, 0, stream>>>((const float4*)Mu, (S4*)MuB, 3*65536/4);
    k_cast4<<<dim3(NKF*65536/4/256), 256, 0, stream>>>((const float4*)Mp, (S4*)MpB, NKF*65536/4);
    k_cast4<<<dim3(NKF*65536/4/256), 256, 0, stream>>>((const float4*)Mm, (S4*)MmB, NKF*65536/4);
    k_transpose<<<dim3((SLEN*NKF+255)/256), 256, 0, stream>>>(phi, phiT, SLEN, NKF);
    k_toep<<<dim3(NKF*16*128*64/256), 256, 0, stream>>>(phiT, Tt);
    k_transpose<<<dim3((DIM*NH+255)/256), 256, 0, stream>>>(w1, w1T, DIM, NH);
    k_transpose<<<dim3((DIM*NH+255)/256), 256, 0, stream>>>(vv, vT, DIM, NH);
    k_transpose<<<dim3((NH*DIM+255)/256), 256, 0, stream>>>(w2, w2T, NH, DIM);
    k_buildM<<<dim3(1024), 256, 0, stream>>>(my, pw, pwT);

    // rmsnorm
    k_rmsnorm<<<dim3(NROW), 256, 0, stream>>>(x, rmsw, u_b);

    // companion-matrix powers via doubling (bf16, f32 accumulate)
    const int ns[6]   = {1, 2, 4, 8, 16, 32};
    const int cnts[6] = {1, 2, 4, 8, 16, 31};
    for (int s = 0; s < 6; ++s)
        k_pow<<<dim3(4, 2, cnts[s]), 512, 0, stream>>>(pw, pwT, ns[s], 1);

    // y = ar_u
    k_aru<<<dim3(16, NB), 512, 0, stream>>>(u_b, MuB, y);

    // spectral
    if (pmcount == 2){
        k_proj<<<dim3(16, NB, NKF), 512, 0, stream>>>(u_b, MpB, sigma, V, 0);
        k_proj<<<dim3(16, NB, NKF), 512, 0, stream>>>(u_b, MmB, sigma, V + VELEMS, 1);
        k_conv<<<dim3(72, NB, KG), 512, 0, stream>>>(V, Tt, y, 2);
    } else {
        k_proj<<<dim3(16, NB, NKF), 512, 0, stream>>>(u_b, MpB, sigma, V, 0);
        k_conv<<<dim3(72, NB, KG), 512, 0, stream>>>(V, Tt, y, 1);
        k_proj<<<dim3(16, NB, NKF), 512, 0, stream>>>(u_b, MmB, sigma, V, 1);
        k_conv<<<dim3(72, NB, KG), 512, 0, stream>>>(V, Tt, y, 1);
    }

    // output AR recurrence via truncated Q-filter (P=64)
    k_yinit<<<dim3(NTOT/4/256), 256, 0, stream>>>((const float4*)y, (float4*)yhat, (S4*)ybf);
    k_qconv<<<dim3(16, NB, 8), 512, 0, stream>>>(ybf, pw, yhat);
    k_cast4<<<dim3(NTOT/4/256), 256, 0, stream>>>((const float4*)yhat, (S4*)yhbf, NTOT/4);

    // MLP + residuals
    k_mlp1<<<dim3(16, NB, 8), 512, 0, stream>>>(yhbf, w1T, vT, h1T, gT);
    k_act<<<dim3(NH*NROW/8/256), 256, 0, stream>>>((const U4*)h1T, (const U4*)gT, (U4*)actT);
    k_outinit<<<dim3(NTOT/4/256), 256, 0, stream>>>((const float4*)x, (const float4*)yhat, (float4*)out);
    k_mlp2<<<dim3(16, NB, 4), 512, 0, stream>>>(actT, w2T, out);
}